// Round 1
// baseline (815.292 us; speedup 1.0000x reference)
//
#include <hip/hip_runtime.h>

// GIN (5 layers) + BN + pool + MLP head, fused pipeline for MI355X.
// Design:
//  - xw = x @ W1a precomputed (layer-1 gather then runs at 64-dim: linearity of GEMM over segment_sum)
//  - ELL adjacency built once per launch (atomic slot alloc), reused by all 5 layers
//  - BN folded into next consumer: v = scale*(h_own + sum_src h) + (1+deg)*shift
//  - per-layer fused kernel: gather -> GEMM1+ReLU -> GEMM2+ReLU -> store + BN stats
//  - pool+head fused: block per graph (batch is sorted -> binary search range)

constexpr int N = 50000;
constexpr int E = 800000;
constexpr int G = 128;
constexpr int MAXDEG = 64;
constexpr float BN_EPS = 1e-5f;

__global__ __launch_bounds__(256) void count_fill_kernel(
    const int* __restrict__ ei, int* __restrict__ deg, int* __restrict__ ell)
{
    int e = blockIdx.x * 256 + threadIdx.x;
    if (e < E) {
        int s = ei[e];
        int d = ei[E + e];
        int slot = atomicAdd(&deg[d], 1);
        if (slot < MAXDEG) ell[d * MAXDEG + slot] = s;
    }
}

// out[n][64] = x[n][128] @ W[128][64]
__global__ __launch_bounds__(256) void xw_kernel(
    const float* __restrict__ x, const float* __restrict__ W, float* __restrict__ out)
{
    extern __shared__ float smem[];
    float* sX = smem;          // 64*128
    float* sW = smem + 8192;   // 128*64
    int tid = threadIdx.x;
    int base = blockIdx.x * 64;

    for (int i = tid; i < 2048; i += 256)
        ((float4*)sW)[i] = ((const float4*)W)[i];
    for (int i = tid; i < 2048; i += 256) {
        int r = i >> 5, c4 = i & 31;
        int node = base + r;
        float4 v = make_float4(0.f, 0.f, 0.f, 0.f);
        if (node < N) v = ((const float4*)(x + (size_t)node * 128))[c4];
        *(float4*)(sX + r * 128 + c4 * 4) = v;
    }
    __syncthreads();

    int ty = tid >> 4, tx = tid & 15;
    float acc[4][4];
#pragma unroll
    for (int r = 0; r < 4; r++)
#pragma unroll
        for (int cc = 0; cc < 4; cc++) acc[r][cc] = 0.f;

    for (int c = 0; c < 128; c++) {
        float4 w4 = *(const float4*)(sW + c * 64 + 4 * tx);
#pragma unroll
        for (int r = 0; r < 4; r++) {
            float a = sX[(4 * ty + r) * 128 + c];
            acc[r][0] += a * w4.x; acc[r][1] += a * w4.y;
            acc[r][2] += a * w4.z; acc[r][3] += a * w4.w;
        }
    }
#pragma unroll
    for (int r = 0; r < 4; r++) {
        int node = base + 4 * ty + r;
        if (node < N)
            ((float4*)(out + (size_t)node * 64))[tx] =
                make_float4(acc[r][0], acc[r][1], acc[r][2], acc[r][3]);
    }
}

// Fused GIN layer.
// FIRST=true:  v = relu(own + sum_src + b1a), then GEMM2(W2,b2)+relu  (GEMM1 done by xw_kernel)
// FIRST=false: v = scale*(own+sum) + (1+deg)*shift, GEMM1(W1,b1)+relu, GEMM2(W2,b2)+relu
// Always: write hout (pre-BN), accumulate per-channel sum/sumsq into statsOut.
template <bool FIRST>
__global__ __launch_bounds__(256) void layer_kernel(
    const float* __restrict__ hin, const int* __restrict__ ell, const int* __restrict__ deg,
    const float* __restrict__ statsPrev, const float* __restrict__ gamma, const float* __restrict__ beta,
    const float* __restrict__ bias0,
    const float* __restrict__ W1, const float* __restrict__ b1,
    const float* __restrict__ W2, const float* __restrict__ b2,
    float* __restrict__ hout, float* __restrict__ statsOut)
{
    extern __shared__ float smem[];
    float* sW2   = smem;               // 4096
    float* sV    = sW2 + 4096;         // 64*68 (padded stride: 2-way-only conflicts)
    float* sStat = sV + 64 * 68;       // 128
    float* sW1   = sStat + 128;        // 4096 (also reused as H buffer, stride 64)

    int tid = threadIdx.x, lane = tid & 63, wv = tid >> 6;

    for (int i = tid; i < 1024; i += 256)
        ((float4*)sW2)[i] = ((const float4*)W2)[i];
    if constexpr (!FIRST) {
        for (int i = tid; i < 1024; i += 256)
            ((float4*)sW1)[i] = ((const float4*)W1)[i];
    }
    if (tid < 128) sStat[tid] = 0.f;

    float r_scale = 1.f, r_shift = 0.f, r_b0 = 0.f;
    if constexpr (FIRST) {
        r_b0 = bias0[lane];
    } else {
        float mean = statsPrev[lane] * (1.f / N);
        float var  = statsPrev[64 + lane] * (1.f / N) - mean * mean;
        r_scale = gamma[lane] * rsqrtf(var + BN_EPS);
        r_shift = beta[lane] - mean * r_scale;
    }
    __syncthreads();

    int base = blockIdx.x * 64;

    // ---- phase A: gather (wave-per-node, lane = channel) ----
    for (int k = 0; k < 16; k++) {
        int node = base + wv * 16 + k;
        float v = 0.f;
        if (node < N) {
            int dg  = deg[node];
            int dgc = min(dg, MAXDEG);
            const int* row = ell + node * MAXDEG;   // wave-uniform addresses -> scalar loads
            float a0 = 0.f, a1 = 0.f, a2 = 0.f, a3 = 0.f;
            int j = 0;
            for (; j + 3 < dgc; j += 4) {
                int s0 = row[j], s1 = row[j + 1], s2 = row[j + 2], s3 = row[j + 3];
                a0 += hin[s0 * 64 + lane];
                a1 += hin[s1 * 64 + lane];
                a2 += hin[s2 * 64 + lane];
                a3 += hin[s3 * 64 + lane];
            }
            for (; j < dgc; j++) a0 += hin[row[j] * 64 + lane];
            float sum = ((a0 + a1) + (a2 + a3)) + hin[node * 64 + lane];
            if constexpr (FIRST) v = fmaxf(sum + r_b0, 0.f);
            else                 v = r_scale * sum + (float)(1 + dg) * r_shift;
        }
        sV[(wv * 16 + k) * 68 + lane] = v;
    }
    __syncthreads();

    int ty = tid >> 4, tx = tid & 15;
    const float* Bsrc = sV;
    int bstride = 68;

    if constexpr (!FIRST) {
        // ---- phase B: H = relu(V @ W1 + b1) ----
        float acc[4][4];
#pragma unroll
        for (int cc = 0; cc < 4; cc++) {
            float b = b1[4 * tx + cc];
            acc[0][cc] = b; acc[1][cc] = b; acc[2][cc] = b; acc[3][cc] = b;
        }
        for (int c = 0; c < 64; c++) {
            float4 w4 = *(const float4*)(sW1 + c * 64 + 4 * tx);
#pragma unroll
            for (int r = 0; r < 4; r++) {
                float a = sV[(4 * ty + r) * 68 + c];
                acc[r][0] += a * w4.x; acc[r][1] += a * w4.y;
                acc[r][2] += a * w4.z; acc[r][3] += a * w4.w;
            }
        }
        __syncthreads();   // all reads of sW1 done; reuse its space for H
#pragma unroll
        for (int r = 0; r < 4; r++)
#pragma unroll
            for (int cc = 0; cc < 4; cc++)
                sW1[(4 * ty + r) * 64 + 4 * tx + cc] = fmaxf(acc[r][cc], 0.f);
        __syncthreads();
        Bsrc = sW1;
        bstride = 64;
    }

    // ---- phase C: O = relu(B @ W2 + b2), store, stats ----
    float acc[4][4];
#pragma unroll
    for (int cc = 0; cc < 4; cc++) {
        float b = b2[4 * tx + cc];
        acc[0][cc] = b; acc[1][cc] = b; acc[2][cc] = b; acc[3][cc] = b;
    }
    for (int c = 0; c < 64; c++) {
        float4 w4 = *(const float4*)(sW2 + c * 64 + 4 * tx);
#pragma unroll
        for (int r = 0; r < 4; r++) {
            float a = Bsrc[(4 * ty + r) * bstride + c];
            acc[r][0] += a * w4.x; acc[r][1] += a * w4.y;
            acc[r][2] += a * w4.z; acc[r][3] += a * w4.w;
        }
    }
#pragma unroll
    for (int r = 0; r < 4; r++) {
        int node = base + 4 * ty + r;
        if (node < N) {
            float4 st;
            st.x = fmaxf(acc[r][0], 0.f); st.y = fmaxf(acc[r][1], 0.f);
            st.z = fmaxf(acc[r][2], 0.f); st.w = fmaxf(acc[r][3], 0.f);
            acc[r][0] = st.x; acc[r][1] = st.y; acc[r][2] = st.z; acc[r][3] = st.w;
            ((float4*)(hout + (size_t)node * 64))[tx] = st;
        } else {
            acc[r][0] = acc[r][1] = acc[r][2] = acc[r][3] = 0.f;
        }
    }
#pragma unroll
    for (int cc = 0; cc < 4; cc++) {
        float s = 0.f, q = 0.f;
#pragma unroll
        for (int r = 0; r < 4; r++) { s += acc[r][cc]; q += acc[r][cc] * acc[r][cc]; }
        atomicAdd(&sStat[4 * tx + cc], s);
        atomicAdd(&sStat[64 + 4 * tx + cc], q);
    }
    __syncthreads();
    if (tid < 128) atomicAdd(&statsOut[tid], sStat[tid]);
}

// pooled[g] = scale*sum_{n in g} h[n] + cnt*shift ; then z=relu(p@fc1+b1); z2=z@fc2+b2; log_softmax
__global__ __launch_bounds__(256) void pool_head_kernel(
    const float* __restrict__ h, const int* __restrict__ batch,
    const float* __restrict__ stats, const float* __restrict__ gamma, const float* __restrict__ beta,
    const float* __restrict__ fc1w, const float* __restrict__ fc1b,
    const float* __restrict__ fc2w, const float* __restrict__ fc2b,
    float* __restrict__ out)
{
    __shared__ float sacc[4][64];
    __shared__ float sp[64];
    __shared__ float sz[64];
    __shared__ float so[10];

    int g = blockIdx.x;
    int lane = threadIdx.x & 63, wv = threadIdx.x >> 6;

    // lower_bound(g), lower_bound(g+1) over sorted batch (uniform -> scalar)
    int start, end;
    {
        int lo = 0, hi = N;
        while (lo < hi) { int mid = (lo + hi) >> 1; if (batch[mid] < g) lo = mid + 1; else hi = mid; }
        start = lo;
        lo = start; hi = N;
        while (lo < hi) { int mid = (lo + hi) >> 1; if (batch[mid] < g + 1) lo = mid + 1; else hi = mid; }
        end = lo;
    }

    float acc = 0.f;
    for (int node = start + wv; node < end; node += 4)
        acc += h[(size_t)node * 64 + lane];
    sacc[wv][lane] = acc;
    __syncthreads();

    if (wv == 0) {
        float mean = stats[lane] * (1.f / N);
        float var  = stats[64 + lane] * (1.f / N) - mean * mean;
        float sc = gamma[lane] * rsqrtf(var + BN_EPS);
        float sh = beta[lane] - mean * sc;
        float t = sacc[0][lane] + sacc[1][lane] + sacc[2][lane] + sacc[3][lane];
        sp[lane] = sc * t + (float)(end - start) * sh;
    }
    __syncthreads();
    if (wv == 0) {
        float a = fc1b[lane];
#pragma unroll
        for (int c = 0; c < 64; c++) a += sp[c] * fc1w[c * 64 + lane];
        sz[lane] = fmaxf(a, 0.f);
    }
    __syncthreads();
    if (wv == 0 && lane < 10) {
        float z = fc2b[lane];
#pragma unroll
        for (int j = 0; j < 64; j++) z += sz[j] * fc2w[j * 10 + lane];
        so[lane] = z;
    }
    __syncthreads();
    if (wv == 0 && lane < 10) {
        float m = -1e30f;
#pragma unroll
        for (int c = 0; c < 10; c++) m = fmaxf(m, so[c]);
        float s = 0.f;
#pragma unroll
        for (int c = 0; c < 10; c++) s += expf(so[c] - m);
        out[g * 10 + lane] = so[lane] - m - logf(s);
    }
}

extern "C" void kernel_launch(void* const* d_in, const int* in_sizes, int n_in,
                              void* d_out, int out_size, void* d_ws, size_t ws_size,
                              hipStream_t stream)
{
    const float* x    = (const float*)d_in[0];
    const int*   ei   = (const int*)  d_in[1];
    const int*   batch= (const int*)  d_in[2];
    const float* W1a  = (const float*)d_in[3];
    const float* b1a  = (const float*)d_in[4];
    const float* W1b  = (const float*)d_in[5];
    const float* b1b  = (const float*)d_in[6];
    const float* Wa   = (const float*)d_in[7];
    const float* ba   = (const float*)d_in[8];
    const float* Wb   = (const float*)d_in[9];
    const float* bb   = (const float*)d_in[10];
    const float* gammas = (const float*)d_in[11];
    const float* betas  = (const float*)d_in[12];
    const float* fc1w = (const float*)d_in[13];
    const float* fc1b = (const float*)d_in[14];
    const float* fc2w = (const float*)d_in[15];
    const float* fc2b = (const float*)d_in[16];
    float* out = (float*)d_out;

    // workspace carve (all 256-aligned by construction)
    char* w = (char*)d_ws;
    int*   deg   = (int*)w;                          // N ints        @ 0       (zeroed)
    float* stats = (float*)(w + 200000);             // 5*128 floats  @ 200000  (zeroed)
    int*   ell   = (int*)(w + 202752);               // N*64 ints
    float* bufA  = (float*)(w + 13002752);           // N*64 floats
    float* bufB  = (float*)(w + 25802752);           // N*64 floats

    hipMemsetAsync(d_ws, 0, 202560, stream);

    count_fill_kernel<<<(E + 255) / 256, 256, 0, stream>>>(ei, deg, ell);

    size_t ldsXW = (size_t)(8192 + 8192) * sizeof(float);           // 64 KB
    xw_kernel<<<(N + 63) / 64, 256, ldsXW, stream>>>(x, W1a, bufA);

    int nb = (N + 63) / 64;
    size_t lds1 = (size_t)(4096 + 64 * 68 + 128) * sizeof(float);           // ~34 KB
    size_t lds2 = (size_t)(4096 + 64 * 68 + 128 + 4096) * sizeof(float);    // ~50 KB

    layer_kernel<true><<<nb, 256, lds1, stream>>>(
        bufA, ell, deg, nullptr, nullptr, nullptr, b1a,
        nullptr, nullptr, W1b, b1b, bufB, stats);

    layer_kernel<false><<<nb, 256, lds2, stream>>>(
        bufB, ell, deg, stats, gammas, betas, nullptr,
        Wa, ba, Wb, bb, bufA, stats + 128);

    layer_kernel<false><<<nb, 256, lds2, stream>>>(
        bufA, ell, deg, stats + 128, gammas + 64, betas + 64, nullptr,
        Wa + 4096, ba + 64, Wb + 4096, bb + 64, bufB, stats + 256);

    layer_kernel<false><<<nb, 256, lds2, stream>>>(
        bufB, ell, deg, stats + 256, gammas + 128, betas + 128, nullptr,
        Wa + 8192, ba + 128, Wb + 8192, bb + 128, bufA, stats + 384);

    layer_kernel<false><<<nb, 256, lds2, stream>>>(
        bufA, ell, deg, stats + 384, gammas + 192, betas + 192, nullptr,
        Wa + 12288, ba + 192, Wb + 12288, bb + 192, bufB, stats + 512);

    pool_head_kernel<<<G, 256, 0, stream>>>(
        bufB, batch, stats + 512, gammas + 256, betas + 256,
        fc1w, fc1b, fc2w, fc2b, out);
}

// Round 2
// 530.485 us; speedup vs baseline: 1.5369x; 1.5369x over previous
//
#include <hip/hip_runtime.h>

// GIN (5 layers) + BN + pool + MLP head, fused pipeline for MI355X. Round 2.
// Changes vs R1 (which was latency-bound: VALUBusy 11%, occ 19%, HBM 8.6%):
//  - gather restructured: lane=(node4,feat4), float4 loads, int4 idx loads,
//    neighbor unroll x4 with zero-row padding -> 16x bytes in flight per wave
//  - weights read from global (L1-broadcast) instead of LDS; H in-place in sV
//    -> LDS 50KB -> 17.9KB -> 8 blocks/CU
//  - xw_kernel LDS-free

constexpr int N = 50000;
constexpr int E = 800000;
constexpr int G = 128;
constexpr int MAXDEG = 64;
constexpr float BN_EPS = 1e-5f;

__device__ inline float4 ld4(const float* p) { return *(const float4*)p; }
__device__ inline void st4(float* p, float4 v) { *(float4*)p = v; }
__device__ inline float4 add4(float4 a, float4 b) {
    return make_float4(a.x + b.x, a.y + b.y, a.z + b.z, a.w + b.w);
}

__global__ __launch_bounds__(256) void count_fill_kernel(
    const int* __restrict__ ei, int* __restrict__ deg, int* __restrict__ ell)
{
    int e = blockIdx.x * 256 + threadIdx.x;
    if (e < E) {
        int s = ei[e];
        int d = ei[E + e];
        int slot = atomicAdd(&deg[d], 1);
        if (slot < MAXDEG) ell[d * MAXDEG + slot] = s;
    }
}

// pad each ELL row to a multiple of 4 slots with the zero-row index N
__global__ __launch_bounds__(256) void pad_kernel(
    const int* __restrict__ deg, int* __restrict__ ell)
{
    int n = blockIdx.x * 256 + threadIdx.x;
    if (n < N) {
        int dgc = min(deg[n], MAXDEG);
        int p = (dgc + 3) & ~3;
        for (int s = dgc; s < p; s++) ell[n * MAXDEG + s] = N;
    }
}

// out[n][64] = x[n][128] @ W[128][64]; no LDS (x rows broadcast via L1)
__global__ __launch_bounds__(256) void xw_kernel(
    const float* __restrict__ x, const float* __restrict__ W, float* __restrict__ out)
{
    int tid = threadIdx.x;
    int ty = tid >> 4, tx = tid & 15;
    int base = blockIdx.x * 64;

    float acc[4][4];
#pragma unroll
    for (int r = 0; r < 4; r++)
#pragma unroll
        for (int cc = 0; cc < 4; cc++) acc[r][cc] = 0.f;

    int rr[4];
#pragma unroll
    for (int r = 0; r < 4; r++) rr[r] = min(base + 4 * ty + r, N - 1);

#pragma unroll 4
    for (int c = 0; c < 128; c++) {
        float4 w4 = ld4(W + c * 64 + 4 * tx);
#pragma unroll
        for (int r = 0; r < 4; r++) {
            float a = x[(size_t)rr[r] * 128 + c];
            acc[r][0] += a * w4.x; acc[r][1] += a * w4.y;
            acc[r][2] += a * w4.z; acc[r][3] += a * w4.w;
        }
    }
#pragma unroll
    for (int r = 0; r < 4; r++) {
        int node = base + 4 * ty + r;
        if (node < N)
            st4(out + (size_t)node * 64 + 4 * tx,
                make_float4(acc[r][0], acc[r][1], acc[r][2], acc[r][3]));
    }
}

// Fused GIN layer. hin has N+1 rows (row N = zeros).
// FIRST:  v = relu(own + sum_src + b1a)           then GEMM2(W2,b2)+relu
// !FIRST: v = scale*(own+sum) + (1+deg)*shift, GEMM1(W1,b1)+relu (in-place), GEMM2+relu
// Writes hout (pre-BN, post-relu) and accumulates channel sum/sumsq into statsOut.
template <bool FIRST>
__global__ __launch_bounds__(256) void layer_kernel(
    const float* __restrict__ hin, const int* __restrict__ ell, const int* __restrict__ deg,
    const float* __restrict__ statsPrev, const float* __restrict__ gamma, const float* __restrict__ beta,
    const float* __restrict__ bias0,
    const float* __restrict__ W1, const float* __restrict__ b1,
    const float* __restrict__ W2, const float* __restrict__ b2,
    float* __restrict__ hout, float* __restrict__ statsOut)
{
    __shared__ float sV[64 * 68];   // stride 68
    __shared__ float sStat[128];

    int tid = threadIdx.x, lane = tid & 63, wv = tid >> 6;
    if (tid < 128) sStat[tid] = 0.f;

    int base = blockIdx.x * 64;
    int n4 = lane >> 4, f = lane & 15;   // node-sub, feature-quad

    // per-lane channel quad f*4..f*4+3 epilogue params
    float4 sc4 = make_float4(1.f, 1.f, 1.f, 1.f);
    float4 sh4 = make_float4(0.f, 0.f, 0.f, 0.f);
    float4 b04 = make_float4(0.f, 0.f, 0.f, 0.f);
    if constexpr (FIRST) {
        b04 = ld4(bias0 + 4 * f);
    } else {
        float4 s1 = ld4(statsPrev + 4 * f);
        float4 s2 = ld4(statsPrev + 64 + 4 * f);
        float4 g4 = ld4(gamma + 4 * f);
        float4 be4 = ld4(beta + 4 * f);
        float mx = s1.x / N, my = s1.y / N, mz = s1.z / N, mw = s1.w / N;
        sc4.x = g4.x * rsqrtf(s2.x / N - mx * mx + BN_EPS);
        sc4.y = g4.y * rsqrtf(s2.y / N - my * my + BN_EPS);
        sc4.z = g4.z * rsqrtf(s2.z / N - mz * mz + BN_EPS);
        sc4.w = g4.w * rsqrtf(s2.w / N - mw * mw + BN_EPS);
        sh4.x = be4.x - mx * sc4.x; sh4.y = be4.y - my * sc4.y;
        sh4.z = be4.z - mz * sc4.z; sh4.w = be4.w - mw * sc4.w;
    }

    // ---- phase A: gather; wave handles 4 nodes at a time ----
#pragma unroll
    for (int kk = 0; kk < 4; kk++) {
        int node = base + wv * 16 + kk * 4 + n4;
        int nd = (node < N) ? node : N;
        int dg = (node < N) ? deg[node] : 0;
        int dgc = min(dg, MAXDEG);
        int p = (dgc + 3) & ~3;
        const int* row = ell + (size_t)nd * MAXDEG;

        float4 a0 = make_float4(0.f, 0.f, 0.f, 0.f), a1 = a0, a2 = a0, a3 = a0;
        for (int j = 0; j < p; j += 4) {
            int4 iv = *(const int4*)(row + j);
            a0 = add4(a0, ld4(hin + (size_t)iv.x * 64 + 4 * f));
            a1 = add4(a1, ld4(hin + (size_t)iv.y * 64 + 4 * f));
            a2 = add4(a2, ld4(hin + (size_t)iv.z * 64 + 4 * f));
            a3 = add4(a3, ld4(hin + (size_t)iv.w * 64 + 4 * f));
        }
        float4 own = ld4(hin + (size_t)nd * 64 + 4 * f);
        float4 s = add4(add4(add4(a0, a1), add4(a2, a3)), own);
        float4 v;
        if constexpr (FIRST) {
            v = make_float4(fmaxf(s.x + b04.x, 0.f), fmaxf(s.y + b04.y, 0.f),
                            fmaxf(s.z + b04.z, 0.f), fmaxf(s.w + b04.w, 0.f));
        } else {
            float dsh = (float)(1 + dg);
            v = make_float4(sc4.x * s.x + dsh * sh4.x, sc4.y * s.y + dsh * sh4.y,
                            sc4.z * s.z + dsh * sh4.z, sc4.w * s.w + dsh * sh4.w);
        }
        st4(sV + (wv * 16 + kk * 4 + n4) * 68 + 4 * f, v);
    }
    __syncthreads();

    int ty = tid >> 4, tx = tid & 15;

    if constexpr (!FIRST) {
        // ---- phase B: H = relu(V @ W1 + b1), in-place into sV ----
        float acc[4][4];
#pragma unroll
        for (int cc = 0; cc < 4; cc++) {
            float b = b1[4 * tx + cc];
            acc[0][cc] = b; acc[1][cc] = b; acc[2][cc] = b; acc[3][cc] = b;
        }
#pragma unroll 4
        for (int c = 0; c < 64; c++) {
            float4 w4 = ld4(W1 + c * 64 + 4 * tx);
#pragma unroll
            for (int r = 0; r < 4; r++) {
                float a = sV[(4 * ty + r) * 68 + c];
                acc[r][0] += a * w4.x; acc[r][1] += a * w4.y;
                acc[r][2] += a * w4.z; acc[r][3] += a * w4.w;
            }
        }
        __syncthreads();
#pragma unroll
        for (int r = 0; r < 4; r++)
            st4(sV + (4 * ty + r) * 68 + 4 * tx,
                make_float4(fmaxf(acc[r][0], 0.f), fmaxf(acc[r][1], 0.f),
                            fmaxf(acc[r][2], 0.f), fmaxf(acc[r][3], 0.f)));
        __syncthreads();
    }

    // ---- phase C: O = relu(V @ W2 + b2), store, stats ----
    float acc[4][4];
#pragma unroll
    for (int cc = 0; cc < 4; cc++) {
        float b = b2[4 * tx + cc];
        acc[0][cc] = b; acc[1][cc] = b; acc[2][cc] = b; acc[3][cc] = b;
    }
#pragma unroll 4
    for (int c = 0; c < 64; c++) {
        float4 w4 = ld4(W2 + c * 64 + 4 * tx);
#pragma unroll
        for (int r = 0; r < 4; r++) {
            float a = sV[(4 * ty + r) * 68 + c];
            acc[r][0] += a * w4.x; acc[r][1] += a * w4.y;
            acc[r][2] += a * w4.z; acc[r][3] += a * w4.w;
        }
    }
#pragma unroll
    for (int r = 0; r < 4; r++) {
        int node = base + 4 * ty + r;
        if (node < N) {
            float4 st;
            st.x = fmaxf(acc[r][0], 0.f); st.y = fmaxf(acc[r][1], 0.f);
            st.z = fmaxf(acc[r][2], 0.f); st.w = fmaxf(acc[r][3], 0.f);
            acc[r][0] = st.x; acc[r][1] = st.y; acc[r][2] = st.z; acc[r][3] = st.w;
            st4(hout + (size_t)node * 64 + 4 * tx, st);
        } else {
            acc[r][0] = acc[r][1] = acc[r][2] = acc[r][3] = 0.f;
        }
    }
#pragma unroll
    for (int cc = 0; cc < 4; cc++) {
        float s = 0.f, q = 0.f;
#pragma unroll
        for (int r = 0; r < 4; r++) { s += acc[r][cc]; q += acc[r][cc] * acc[r][cc]; }
        atomicAdd(&sStat[4 * tx + cc], s);
        atomicAdd(&sStat[64 + 4 * tx + cc], q);
    }
    __syncthreads();
    if (tid < 128) atomicAdd(&statsOut[tid], sStat[tid]);
}

// pooled[g] = scale*sum_{n in g} h[n] + cnt*shift; z=relu(p@fc1+b1); z@fc2+b2; log_softmax
__global__ __launch_bounds__(256) void pool_head_kernel(
    const float* __restrict__ h, const int* __restrict__ batch,
    const float* __restrict__ stats, const float* __restrict__ gamma, const float* __restrict__ beta,
    const float* __restrict__ fc1w, const float* __restrict__ fc1b,
    const float* __restrict__ fc2w, const float* __restrict__ fc2b,
    float* __restrict__ out)
{
    __shared__ float sacc[4][64];
    __shared__ float sp[64];
    __shared__ float sz[64];
    __shared__ float so[10];

    int g = blockIdx.x;
    int lane = threadIdx.x & 63, wv = threadIdx.x >> 6;

    int start, end;
    {
        int lo = 0, hi = N;
        while (lo < hi) { int mid = (lo + hi) >> 1; if (batch[mid] < g) lo = mid + 1; else hi = mid; }
        start = lo;
        lo = start; hi = N;
        while (lo < hi) { int mid = (lo + hi) >> 1; if (batch[mid] < g + 1) lo = mid + 1; else hi = mid; }
        end = lo;
    }

    float acc = 0.f;
    for (int node = start + wv; node < end; node += 4)
        acc += h[(size_t)node * 64 + lane];
    sacc[wv][lane] = acc;
    __syncthreads();

    if (wv == 0) {
        float mean = stats[lane] * (1.f / N);
        float var  = stats[64 + lane] * (1.f / N) - mean * mean;
        float sc = gamma[lane] * rsqrtf(var + BN_EPS);
        float sh = beta[lane] - mean * sc;
        float t = sacc[0][lane] + sacc[1][lane] + sacc[2][lane] + sacc[3][lane];
        sp[lane] = sc * t + (float)(end - start) * sh;
    }
    __syncthreads();
    if (wv == 0) {
        float a = fc1b[lane];
#pragma unroll
        for (int c = 0; c < 64; c++) a += sp[c] * fc1w[c * 64 + lane];
        sz[lane] = fmaxf(a, 0.f);
    }
    __syncthreads();
    if (wv == 0 && lane < 10) {
        float z = fc2b[lane];
#pragma unroll
        for (int j = 0; j < 64; j++) z += sz[j] * fc2w[j * 10 + lane];
        so[lane] = z;
    }
    __syncthreads();
    if (wv == 0 && lane < 10) {
        float m = -1e30f;
#pragma unroll
        for (int c = 0; c < 10; c++) m = fmaxf(m, so[c]);
        float s = 0.f;
#pragma unroll
        for (int c = 0; c < 10; c++) s += expf(so[c] - m);
        out[g * 10 + lane] = so[lane] - m - logf(s);
    }
}

extern "C" void kernel_launch(void* const* d_in, const int* in_sizes, int n_in,
                              void* d_out, int out_size, void* d_ws, size_t ws_size,
                              hipStream_t stream)
{
    const float* x    = (const float*)d_in[0];
    const int*   ei   = (const int*)  d_in[1];
    const int*   batch= (const int*)  d_in[2];
    const float* W1a  = (const float*)d_in[3];
    const float* b1a  = (const float*)d_in[4];
    const float* W1b  = (const float*)d_in[5];
    const float* b1b  = (const float*)d_in[6];
    const float* Wa   = (const float*)d_in[7];
    const float* ba   = (const float*)d_in[8];
    const float* Wb   = (const float*)d_in[9];
    const float* bb   = (const float*)d_in[10];
    const float* gammas = (const float*)d_in[11];
    const float* betas  = (const float*)d_in[12];
    const float* fc1w = (const float*)d_in[13];
    const float* fc1b = (const float*)d_in[14];
    const float* fc2w = (const float*)d_in[15];
    const float* fc2b = (const float*)d_in[16];
    float* out = (float*)d_out;

    // workspace carve
    char* w = (char*)d_ws;
    int*   deg   = (int*)w;                          // N ints        @ 0        (zeroed)
    float* stats = (float*)(w + 200000);             // 5*128 floats  @ 200000   (zeroed)
    int*   ell   = (int*)(w + 202752);               // N*64 ints
    float* bufA  = (float*)(w + 13002752);           // (N+1)*64 floats
    float* bufB  = (float*)(w + 25803008);           // (N+1)*64 floats

    hipMemsetAsync(d_ws, 0, 202560, stream);
    hipMemsetAsync(bufA + (size_t)N * 64, 0, 256, stream);   // zero row N
    hipMemsetAsync(bufB + (size_t)N * 64, 0, 256, stream);

    count_fill_kernel<<<(E + 255) / 256, 256, 0, stream>>>(ei, deg, ell);
    pad_kernel<<<(N + 255) / 256, 256, 0, stream>>>(deg, ell);
    xw_kernel<<<(N + 63) / 64, 256, 0, stream>>>(x, W1a, bufA);

    int nb = (N + 63) / 64;

    layer_kernel<true><<<nb, 256, 0, stream>>>(
        bufA, ell, deg, nullptr, nullptr, nullptr, b1a,
        nullptr, nullptr, W1b, b1b, bufB, stats);

    layer_kernel<false><<<nb, 256, 0, stream>>>(
        bufB, ell, deg, stats, gammas, betas, nullptr,
        Wa, ba, Wb, bb, bufA, stats + 128);

    layer_kernel<false><<<nb, 256, 0, stream>>>(
        bufA, ell, deg, stats + 128, gammas + 64, betas + 64, nullptr,
        Wa + 4096, ba + 64, Wb + 4096, bb + 64, bufB, stats + 256);

    layer_kernel<false><<<nb, 256, 0, stream>>>(
        bufB, ell, deg, stats + 256, gammas + 128, betas + 128, nullptr,
        Wa + 8192, ba + 128, Wb + 8192, bb + 128, bufA, stats + 384);

    layer_kernel<false><<<nb, 256, 0, stream>>>(
        bufA, ell, deg, stats + 384, gammas + 192, betas + 192, nullptr,
        Wa + 12288, ba + 192, Wb + 12288, bb + 192, bufB, stats + 512);

    pool_head_kernel<<<G, 256, 0, stream>>>(
        bufB, batch, stats + 512, gammas + 256, betas + 256,
        fc1w, fc1b, fc2w, fc2b, out);
}